// Round 1
// baseline (86.122 us; speedup 1.0000x reference)
//
#include <hip/hip_runtime.h>
#include <stdint.h>

typedef unsigned short u16;
typedef __attribute__((ext_vector_type(8))) short bf16x8;
typedef __attribute__((ext_vector_type(8))) u16  u16x8;
typedef __attribute__((ext_vector_type(4))) float f32x4;

// Problem constants
static constexpr int BATCH  = 32;
static constexpr int SEQ    = 1000;
static constexpr int DIM    = 64;
static constexpr int HOUT   = 512;
static constexpr int MINLEN = 985;   // 1000 - 16 + 1
static constexpr int KTOT   = 1024;  // 16*64

// ws layout (bytes)
static constexpr size_t XB_OFF   = 0;                  // x bf16: 2,048,000 + 4096 pad u16
static constexpr size_t WF_OFF   = 4u << 20;           // Weff bf16: 512*1024 u16 = 1 MiB
static constexpr size_t BE_OFF   = 5u << 20;           // beff f32: 512
static constexpr int    XB_TOTAL = 2048000 + 4096;     // padded element count (mult of 2048*8)

__device__ inline u16 f2bf(float f) {
  union { float f; uint32_t u; } v; v.f = f;
  uint32_t r = v.u + 0x7fffu + ((v.u >> 16) & 1u);
  return (u16)(r >> 16);
}

// ---- prep 1: x f32 -> bf16 (+ zero pad tail) ----------------------------
__global__ void pe_prep_x(const float* __restrict__ x, u16* __restrict__ xb) {
  int i = (blockIdx.x * 256 + threadIdx.x) * 8;
  if (i >= XB_TOTAL) return;
  u16x8 o;
  if (i < 2048000) {
    const float4* p = (const float4*)(x + i);
    float4 a = p[0], c = p[1];
    o[0] = f2bf(a.x); o[1] = f2bf(a.y); o[2] = f2bf(a.z); o[3] = f2bf(a.w);
    o[4] = f2bf(c.x); o[5] = f2bf(c.y); o[6] = f2bf(c.z); o[7] = f2bf(c.w);
  } else {
    o = (u16x8)(0);
  }
  *(u16x8*)(xb + i) = o;
}

// ---- prep 2: Weff = (W2 + pad(W1) + pad(W0))/3 in bf16; beff = mean bias --
__global__ void pe_prep_w(const float* __restrict__ W0, const float* __restrict__ W1,
                          const float* __restrict__ W2, const float* __restrict__ b0,
                          const float* __restrict__ b1, const float* __restrict__ b2,
                          u16* __restrict__ Wf, float* __restrict__ beff) {
  int i = blockIdx.x * 256 + threadIdx.x;
  if (i < HOUT * KTOT) {
    int h = i >> 10, j = i & 1023;
    float e = W2[i];
    if (j < 512) e += W1[(h << 9) + j];
    if (j < 256) e += W0[(h << 8) + j];
    Wf[i] = f2bf(e * (1.0f / 3.0f));
  } else if (i < HOUT * KTOT + HOUT) {
    int h = i - HOUT * KTOT;
    beff[h] = (b0[h] + b1[h] + b2[h]) * (1.0f / 3.0f);
  }
}

// ---- GEMM: out[b,l,h] = dot(xb[b, l*64 .. +1024], Wf[h,:]) + beff[h] + pos[l,h]
// 128x128 tile, BK=64, 4 waves (2x2), 16x16x32 bf16 MFMA, global_load_lds staging.
__device__ inline void gload_lds16(const void* g, void* l) {
  __builtin_amdgcn_global_load_lds(
      (const __attribute__((address_space(1))) uint32_t*)g,
      (__attribute__((address_space(3))) uint32_t*)l, 16, 0, 0);
}

__global__ __launch_bounds__(256) void pe_gemm(
    const u16* __restrict__ xb, const u16* __restrict__ Wf,
    const float* __restrict__ beff, const float* __restrict__ pos,
    float* __restrict__ out) {
  __shared__ u16 ldsA[128 * 64];
  __shared__ u16 ldsB[128 * 64];

  const int t    = threadIdx.x;
  const int w    = t >> 6;
  const int lane = t & 63;
  const int b    = blockIdx.z;
  const int l0   = blockIdx.y * 128;
  const int n0   = blockIdx.x * 128;
  const int wr   = w >> 1;          // wave row (0..1) -> 64 rows
  const int wc   = w & 1;           // wave col (0..1) -> 64 cols
  const int lr   = lane & 15;
  const int lk   = (lane >> 4) << 3;

  f32x4 acc[4][4] = {};

  // A tile at K-offset kt*64 is a contiguous 128*64 chunk starting at l0*64 + kt*64
  const u16* Abase = xb + b * (SEQ * DIM) + l0 * 64;
  const u16* Bbase = Wf + (size_t)n0 * KTOT;

  for (int kt = 0; kt < 16; ++kt) {
    // stage A: 4 issues x 256 threads x 16B = 16 KB contiguous
    const u16* Ag = Abase + kt * 64;
    #pragma unroll
    for (int i = 0; i < 4; ++i)
      gload_lds16(Ag + i * 2048 + t * 8, &ldsA[i * 2048 + w * 512]);
    // stage B: row (i*32 + t/8) of Wf tile, 16B per lane, linear in LDS
    #pragma unroll
    for (int i = 0; i < 4; ++i) {
      const u16* Bg = Bbase + (size_t)(i * 32 + (t >> 3)) * KTOT + kt * 64 + (t & 7) * 8;
      gload_lds16(Bg, &ldsB[i * 2048 + w * 512]);
    }
    __syncthreads();

    #pragma unroll
    for (int kk = 0; kk < 2; ++kk) {
      bf16x8 aF[4], bF[4];
      #pragma unroll
      for (int m = 0; m < 4; ++m)
        aF[m] = *(const bf16x8*)&ldsA[(wr * 64 + m * 16 + lr) * 64 + kk * 32 + lk];
      #pragma unroll
      for (int n = 0; n < 4; ++n)
        bF[n] = *(const bf16x8*)&ldsB[(wc * 64 + n * 16 + lr) * 64 + kk * 32 + lk];
      #pragma unroll
      for (int m = 0; m < 4; ++m)
        #pragma unroll
        for (int n = 0; n < 4; ++n)
          acc[m][n] = __builtin_amdgcn_mfma_f32_16x16x32_bf16(aF[m], bF[n], acc[m][n], 0, 0, 0);
    }
    __syncthreads();
  }

  // epilogue: D row = (lane>>4)*4 + r, col = lane&15  [learn_hip m89 verified]
  #pragma unroll
  for (int n = 0; n < 4; ++n) {
    const int h  = n0 + wc * 64 + n * 16 + lr;
    const float bv = beff[h];
    #pragma unroll
    for (int m = 0; m < 4; ++m) {
      const int rowb = l0 + wr * 64 + m * 16 + ((lane >> 4) << 2);
      #pragma unroll
      for (int r = 0; r < 4; ++r) {
        const int l = rowb + r;
        if (l < MINLEN) {
          out[((size_t)b * MINLEN + l) * HOUT + h] =
              acc[m][n][r] + bv + pos[(size_t)l * HOUT + h];
        }
      }
    }
  }
}

extern "C" void kernel_launch(void* const* d_in, const int* in_sizes, int n_in,
                              void* d_out, int out_size, void* d_ws, size_t ws_size,
                              hipStream_t stream) {
  const float* x   = (const float*)d_in[0];
  const float* W0  = (const float*)d_in[1];
  const float* b0  = (const float*)d_in[2];
  const float* W1  = (const float*)d_in[3];
  const float* b1  = (const float*)d_in[4];
  const float* W2  = (const float*)d_in[5];
  const float* b2  = (const float*)d_in[6];
  const float* pos = (const float*)d_in[7];
  float* out = (float*)d_out;

  char* ws  = (char*)d_ws;
  u16*  xbf = (u16*)(ws + XB_OFF);
  u16*  Wf  = (u16*)(ws + WF_OFF);
  float* be = (float*)(ws + BE_OFF);

  // prep x: ceil((2048000+4096)/(256*8)) = 1002 blocks exactly
  hipLaunchKernelGGL(pe_prep_x, dim3(XB_TOTAL / (256 * 8)), dim3(256), 0, stream, x, xbf);
  // prep W/b: (524288+512)/256 = 2050 blocks exactly
  hipLaunchKernelGGL(pe_prep_w, dim3((HOUT * KTOT + HOUT) / 256), dim3(256), 0, stream,
                     W0, W1, W2, b0, b1, b2, Wf, be);
  // GEMM: n-tiles x m-tiles x batch
  hipLaunchKernelGGL(pe_gemm, dim3(HOUT / 128, (MINLEN + 127) / 128, BATCH), dim3(256),
                     0, stream, xbf, Wf, be, pos, out);
}

// Round 2
// 58.022 us; speedup vs baseline: 1.4843x; 1.4843x over previous
//
#include <hip/hip_runtime.h>
#include <stdint.h>

typedef unsigned short u16;
typedef __attribute__((ext_vector_type(8))) short bf16x8;
typedef __attribute__((ext_vector_type(8))) u16  u16x8;
typedef __attribute__((ext_vector_type(4))) float f32x4;

// Problem constants
static constexpr int BATCH  = 32;
static constexpr int SEQ    = 1000;
static constexpr int DIM    = 64;
static constexpr int HOUT   = 512;
static constexpr int MINLEN = 985;   // 1000 - 16 + 1
static constexpr int KTOT   = 1024;  // 16*64
static constexpr int AROWS  = 288;   // 256-row tile + 16 window ext, rounded to 32

// ws layout (bytes)
static constexpr size_t XB_OFF   = 0;                  // x bf16: 2,048,000 + 4096 pad u16
static constexpr size_t WF_OFF   = 4u << 20;           // Weff bf16: 512*1024 u16 = 1 MiB
static constexpr size_t BE_OFF   = 5u << 20;           // beff f32: 512
static constexpr int    XB_TOTAL = 2048000 + 4096;     // padded element count

__device__ inline u16 f2bf(float f) {
  union { float f; uint32_t u; } v; v.f = f;
  uint32_t r = v.u + 0x7fffu + ((v.u >> 16) & 1u);
  return (u16)(r >> 16);
}

// ---- prep 1: x f32 -> bf16 (+ zero pad tail) ----------------------------
__global__ void pe_prep_x(const float* __restrict__ x, u16* __restrict__ xb) {
  int i = (blockIdx.x * 256 + threadIdx.x) * 8;
  if (i >= XB_TOTAL) return;
  u16x8 o;
  if (i < 2048000) {
    const float4* p = (const float4*)(x + i);
    float4 a = p[0], c = p[1];
    o[0] = f2bf(a.x); o[1] = f2bf(a.y); o[2] = f2bf(a.z); o[3] = f2bf(a.w);
    o[4] = f2bf(c.x); o[5] = f2bf(c.y); o[6] = f2bf(c.z); o[7] = f2bf(c.w);
  } else {
    o = (u16x8)(0);
  }
  *(u16x8*)(xb + i) = o;
}

// ---- prep 2: Weff = (W2 + pad(W1) + pad(W0))/3 bf16; beff = mean bias ----
__global__ void pe_prep_w(const float* __restrict__ W0, const float* __restrict__ W1,
                          const float* __restrict__ W2, const float* __restrict__ b0,
                          const float* __restrict__ b1, const float* __restrict__ b2,
                          u16* __restrict__ Wf, float* __restrict__ beff) {
  int i = blockIdx.x * 256 + threadIdx.x;
  if (i < HOUT * KTOT) {
    int h = i >> 10, j = i & 1023;
    float e = W2[i];
    if (j < 512) e += W1[(h << 9) + j];
    if (j < 256) e += W0[(h << 8) + j];
    Wf[i] = f2bf(e * (1.0f / 3.0f));
  } else if (i < HOUT * KTOT + HOUT) {
    int h = i - HOUT * KTOT;
    beff[h] = (b0[h] + b1[h] + b2[h]) * (1.0f / 3.0f);
  }
}

__device__ inline void gload_lds16(const void* g, void* l) {
  __builtin_amdgcn_global_load_lds(
      (const __attribute__((address_space(1))) uint32_t*)g,
      (__attribute__((address_space(3))) uint32_t*)l, 16, 0, 0);
}

// ---- GEMM: out[b,l,h] = dot(window) + beff[h] + pos[l,h]
// M=256 x N=128 tile, BK=64 (= one patch offset per K-step), 8 waves (4x2).
// A (sliding window) persisted in LDS once: A[l, kt*64+j] = xflat[(l+kt)*64+j],
// so K-step kt reads LDS row (l_local + kt). B double-buffered + prefetch.
// XOR swizzle (col16 ^= row&7) via pre-swizzled GLOBAL source (linear LDS dest,
// rule 21) + swizzled ds_read: even 8-lane/16B-slot bank spread.
__global__ __launch_bounds__(512, 4) void pe_gemm(
    const u16* __restrict__ xb, const u16* __restrict__ Wf,
    const float* __restrict__ beff, const float* __restrict__ pos,
    float* __restrict__ out) {
  __shared__ u16 ldsA[AROWS * 64];        // 36,864 B
  __shared__ u16 ldsB[2][128 * 64];       // 32,768 B

  const int t    = threadIdx.x;
  const int w    = t >> 6;
  const int lane = t & 63;
  const int b    = blockIdx.z;
  const int l0   = blockIdx.y * 256;
  const int n0   = blockIdx.x * 128;
  const int wr   = w >> 1;                // 0..3 -> 64-row band
  const int wc   = w & 1;                 // 0..1 -> 64-col band
  const int lr   = lane & 15;
  const int g    = lane >> 4;             // 0..3

  // staging source swizzle: dest chunk row = c*8 + (lane>>3), within-row 16B
  // slot = (lane&7) ^ (row&7) = (lane&7) ^ (lane>>3)   (chunks are 8-row aligned)
  const int srow = lane >> 3;
  const int scol = ((lane & 7) ^ (lane >> 3)) * 8;     // u16 offset in row

  const u16* Ab = xb + b * (SEQ * DIM) + l0 * 64;      // contiguous window panel
  const u16* Bb = Wf + (size_t)n0 * KTOT;

  // ---- prologue: stage all of A (36 KB) + B k-tile 0 ----
  #pragma unroll
  for (int i = 0; i < 4; ++i) {
    int c = w * 4 + i;                                  // chunks 0..31
    gload_lds16(Ab + (c * 8 + srow) * 64 + scol, &ldsA[c * 512]);
  }
  if (w < 4) {
    int c = 32 + w;                                     // chunks 32..35
    gload_lds16(Ab + (c * 8 + srow) * 64 + scol, &ldsA[c * 512]);
  }
  #pragma unroll
  for (int i = 0; i < 2; ++i) {
    int c = w * 2 + i;                                  // 16 chunks = 16 KB
    gload_lds16(Bb + (size_t)(c * 8 + srow) * KTOT + scol, &ldsB[0][c * 512]);
  }
  __syncthreads();

  f32x4 acc[4][4] = {};
  int cur = 0;

  for (int kt = 0; kt < 16; ++kt) {
    // issue next B k-tile into the other buffer BEFORE compute (2-phase)
    if (kt < 15) {
      #pragma unroll
      for (int i = 0; i < 2; ++i) {
        int c = w * 2 + i;
        gload_lds16(Bb + (size_t)(c * 8 + srow) * KTOT + (kt + 1) * 64 + scol,
                    &ldsB[cur ^ 1][c * 512]);
      }
    }
    #pragma unroll
    for (int kk = 0; kk < 2; ++kk) {
      bf16x8 aF[4], bF[4];
      #pragma unroll
      for (int m = 0; m < 4; ++m) {
        int r = wr * 64 + m * 16 + lr + kt;             // window shift: +kt
        aF[m] = *(const bf16x8*)&ldsA[r * 64 + ((kk * 4 + g) ^ (r & 7)) * 8];
      }
      #pragma unroll
      for (int n = 0; n < 4; ++n) {
        int r = wc * 64 + n * 16 + lr;
        bF[n] = *(const bf16x8*)&ldsB[cur][r * 64 + ((kk * 4 + g) ^ (r & 7)) * 8];
      }
      #pragma unroll
      for (int m = 0; m < 4; ++m)
        #pragma unroll
        for (int n = 0; n < 4; ++n)
          acc[m][n] = __builtin_amdgcn_mfma_f32_16x16x32_bf16(aF[m], bF[n], acc[m][n], 0, 0, 0);
    }
    __syncthreads();   // compiler emits vmcnt(0) lgkmcnt(0) drain here
    cur ^= 1;
  }

  // ---- epilogue: D row=(lane>>4)*4+r, col=lane&15 (m89) ----
  #pragma unroll
  for (int n = 0; n < 4; ++n) {
    const int h  = n0 + wc * 64 + n * 16 + lr;
    const float bv = beff[h];
    #pragma unroll
    for (int m = 0; m < 4; ++m) {
      const int rowb = l0 + wr * 64 + m * 16 + (g << 2);
      #pragma unroll
      for (int r = 0; r < 4; ++r) {
        const int l = rowb + r;
        if (l < MINLEN) {
          out[((size_t)b * MINLEN + l) * HOUT + h] =
              acc[m][n][r] + bv + pos[(size_t)l * HOUT + h];
        }
      }
    }
  }
}

extern "C" void kernel_launch(void* const* d_in, const int* in_sizes, int n_in,
                              void* d_out, int out_size, void* d_ws, size_t ws_size,
                              hipStream_t stream) {
  const float* x   = (const float*)d_in[0];
  const float* W0  = (const float*)d_in[1];
  const float* b0  = (const float*)d_in[2];
  const float* W1  = (const float*)d_in[3];
  const float* b1  = (const float*)d_in[4];
  const float* W2  = (const float*)d_in[5];
  const float* b2  = (const float*)d_in[6];
  const float* pos = (const float*)d_in[7];
  float* out = (float*)d_out;

  char* ws  = (char*)d_ws;
  u16*  xbf = (u16*)(ws + XB_OFF);
  u16*  Wf  = (u16*)(ws + WF_OFF);
  float* be = (float*)(ws + BE_OFF);

  hipLaunchKernelGGL(pe_prep_x, dim3(XB_TOTAL / (256 * 8)), dim3(256), 0, stream, x, xbf);
  hipLaunchKernelGGL(pe_prep_w, dim3((HOUT * KTOT + HOUT) / 256), dim3(256), 0, stream,
                     W0, W1, W2, b0, b1, b2, Wf, be);
  // M-tiles: ceil(985/256)=4 (tile 3 partially masked), N-tiles: 4, batch 32
  hipLaunchKernelGGL(pe_gemm, dim3(HOUT / 128, 4, BATCH), dim3(512), 0, stream,
                     xbf, Wf, be, pos, out);
}